// Round 2
// baseline (388.680 us; speedup 1.0000x reference)
//
#include <hip/hip_runtime.h>

#define BIG_T 1.0e9f
constexpr float LOG2E = 1.4426950408889634f;

// ---------------- packed offset table: 123 offsets (r2<=9, sorted by r2), even/odd split ----------------
struct P2 { int x, y; };
struct OffTab { P2 p[62]; };
constexpr int packo(int a, int b, int c) { return (a + 3) | ((b + 3) << 4) | ((c + 3) << 8); }
constexpr OffTab make_off() {
    int dx[123], dy[123], dz[123];
    int n = 0;
    for (int rr = 0; rr <= 9; ++rr)
        for (int a = -3; a <= 3; ++a)
            for (int b = -3; b <= 3; ++b)
                for (int c = -3; c <= 3; ++c)
                    if (a * a + b * b + c * c == rr) { dx[n] = a; dy[n] = b; dz[n] = c; ++n; }
    OffTab t{};
    for (int j = 0; j < 62; ++j) {
        t.p[j].x = packo(dx[2 * j], dy[2 * j], dz[2 * j]);
        int k = 2 * j + 1;
        t.p[j].y = (k < 123) ? packo(dx[k], dy[k], dz[k]) : packo(0, 0, 0);
    }
    return t;
}
__constant__ OffTab OFFT = make_off();

__device__ __forceinline__ float fast_exp2(float x) { return __builtin_amdgcn_exp2f(x); }

// ---------------- prep A: per-LR-voxel sigma reciprocals (record slot 0) + sigma_eff ----------------
__global__ void prepA(const float* __restrict__ sxr, const float* __restrict__ syr,
                      const float* __restrict__ szr, const float* __restrict__ srr,
                      float4* __restrict__ param4, float* __restrict__ sigEff) {
    int t = blockIdx.x * 256 + threadIdx.x;   // 32768 total
    float sx = fmaxf(expf(sxr[t]), 1e-6f);
    float sy = fmaxf(expf(syr[t]), 1e-6f);
    float sz = fmaxf(expf(szr[t]), 1e-6f);
    float sr = fmaxf(expf(srr[t]), 1e-6f);
    float a = 0.5f / (sx * sx);
    float b = 0.5f / (sy * sy);
    float c = 0.5f / (sz * sz);
    float d = 1.0f / (2.0f * sr * sr + 1e-8f);
    param4[2 * t] = make_float4(a, b, c, d);
    sigEff[t] = fmaxf(sx, fmaxf(sy, sz));
}

// ---------------- prep B: guide 64^3 -> 32^3 trilinear-antialias downsample (record slot 1) ----------------
__device__ __forceinline__ void mk_taps(int j, int idx[4], float wt[4]) {
    float s = 0.f;
#pragma unroll
    for (int k = 0; k < 4; ++k) {
        int i = 2 * j - 1 + k;
        float w = (k == 0 || k == 3) ? 0.25f : 0.75f;
        bool ok = (i >= 0) && (i < 64);
        wt[k] = ok ? w : 0.f;
        idx[k] = ok ? i : 0;
        s += wt[k];
    }
    float inv = 1.f / s;
#pragma unroll
    for (int k = 0; k < 4; ++k) wt[k] *= inv;
}

__global__ void prepB(const float* __restrict__ guide, float4* __restrict__ param4) {
    int t = blockIdx.x * 256 + threadIdx.x;   // 32768 total
    int w = t & 31, v = (t >> 5) & 31, u = t >> 10;
    int iu[4], iv[4], iw[4];
    float wu[4], wv[4], ww[4];
    mk_taps(u, iu, wu);
    mk_taps(v, iv, wv);
    mk_taps(w, iw, ww);
    float g0 = 0.f, g1 = 0.f, g2 = 0.f;
#pragma unroll
    for (int a = 0; a < 4; ++a) {
#pragma unroll
        for (int b = 0; b < 4; ++b) {
            float wab = wu[a] * wv[b];
            int base = iu[a] * 4096 + iv[b] * 64;
#pragma unroll
            for (int c = 0; c < 4; ++c) {
                float wt = wab * ww[c];
                int gi = base + iw[c];
                g0 += wt * guide[gi];
                g1 += wt * guide[262144 + gi];
                g2 += wt * guide[524288 + gi];
            }
        }
    }
    param4[2 * t + 1] = make_float4(g0, g1, g2, 0.f);
}

// ---------------- prep T: feat [c][u][v][w] -> featT [u][v][w][c] ----------------
__global__ void prepT(const float* __restrict__ feat, float* __restrict__ featT) {
    __shared__ float tile[32][33];
    int uv = blockIdx.x;            // 1024 blocks, one per (u,v)
    int u = uv >> 5, v = uv & 31;
    int col = threadIdx.x & 31;
    int row = threadIdx.x >> 5;     // 0..7
#pragma unroll
    for (int it = 0; it < 4; ++it) {
        int c = row + it * 8;
        tile[c][col] = feat[((c * 32 + u) * 32 + v) * 32 + col];
    }
    __syncthreads();
#pragma unroll
    for (int it = 0; it < 4; ++it) {
        int w = row + it * 8;
        featT[((u * 32 + v) * 32 + w) * 32 + col] = tile[col][w];
    }
}

// ---------------- main kernel: 2 threads per HR voxel (even/odd offset split) ----------------
__global__ __launch_bounds__(256)
void jbu_main(const float* __restrict__ guide, const float4* __restrict__ param4,
              const float* __restrict__ sigEff, const float* __restrict__ featT,
              float* __restrict__ out) {
    // XCD-bijective swizzle: 2048 blocks, 8 XCDs -> each XCD owns one contiguous bx slab
    int bb = (blockIdx.x & 7) * 256 + (blockIdx.x >> 3);
    int bz = bb & 15, by = (bb >> 4) & 15, bx = bb >> 8;   // tiles: 8 x 16 x 16
    int tid = threadIdx.x;
    int h = tid & 1;
    int lz = (tid >> 1) & 3, ly = (tid >> 3) & 3, lx = tid >> 5;
    int X = bx * 8 + lx, Y = by * 4 + ly, Z = bz * 4 + lz;
    int vox = (X << 12) + (Y << 6) + Z;

    float G0 = guide[vox];
    float G1 = guide[262144 + vox];
    float G2 = guide[524288 + vox];

    // sigma_eff_hr: 2x trilinear upsample with clamped taps -> R2 -> offset count
    int x0 = max((X - 1) >> 1, 0), x1 = min(((X - 1) >> 1) + 1, 31);
    int y0 = max((Y - 1) >> 1, 0), y1 = min(((Y - 1) >> 1) + 1, 31);
    int z0 = max((Z - 1) >> 1, 0), z1 = min(((Z - 1) >> 1) + 1, 31);
    float wx1 = (X & 1) ? 0.25f : 0.75f, wx0 = 1.f - wx1;
    float wy1 = (Y & 1) ? 0.25f : 0.75f, wy0 = 1.f - wy1;
    float wz1 = (Z & 1) ? 0.25f : 0.75f, wz0 = 1.f - wz1;
#define SG(i, j, k) sigEff[((i) * 32 + (j)) * 32 + (k)]
    float se =
        wx0 * (wy0 * (wz0 * SG(x0, y0, z0) + wz1 * SG(x0, y0, z1)) +
               wy1 * (wz0 * SG(x0, y1, z0) + wz1 * SG(x0, y1, z1))) +
        wx1 * (wy0 * (wz0 * SG(x1, y0, z0) + wz1 * SG(x1, y0, z1)) +
               wy1 * (wz0 * SG(x1, y1, z0) + wz1 * SG(x1, y1, z1)));
#undef SG
    float Rf = fminf(fmaxf(ceilf(2.f * se), 1.f), 3.f);
    int R2i = (int)(Rf * Rf + 0.5f);
    int n_th = (R2i >= 9) ? 123 : ((R2i >= 4) ? 33 : 7);
    int jmax = (n_th - h + 1) >> 1;     // # of my offsets: o = 2j + h < n_th

    int ucm3 = (X >> 1) - 3, vcm3 = (Y >> 1) - 3, wcm3 = (Z >> 1) - 3;
    float Xh = (float)X - 0.5f, Yh = (float)Y - 0.5f, Zh = (float)Z - 0.5f;

#define ITER_COMMON                                                      \
    P2 e = OFFT.p[j];                                                    \
    int pk = h ? e.y : e.x;                                              \
    int Ui = min(max(ucm3 + (pk & 15), 0), 31);                          \
    int Vi = min(max(vcm3 + ((pk >> 4) & 15), 0), 31);                   \
    int Wi = min(max(wcm3 + (pk >> 8), 0), 31);                          \
    int ci = (Ui << 10) | (Vi << 5) | Wi;                                \
    float4 A = param4[2 * ci];                                           \
    float4 B = param4[2 * ci + 1];                                       \
    float ddx = fmaf(-2.f, (float)Ui, Xh);                               \
    float ddy = fmaf(-2.f, (float)Vi, Yh);                               \
    float ddz = fmaf(-2.f, (float)Wi, Zh);                               \
    float d0 = G0 - B.x, d1 = G1 - B.y, d2 = G2 - B.z;                   \
    float tt = fmaf(ddx * ddx, A.x, fmaf(ddy * ddy, A.y, ddz * ddz * A.z)); \
    float r2s = fmaf(d0, d0, fmaf(d1, d1, d2 * d2));                     \
    tt = fmaf(r2s, A.w, tt);

    // ---- pass 1: tmin = min over my unmasked offsets of tt (tt = -log_w) ----
    float tmin = BIG_T;
#pragma unroll 2
    for (int j = 0; j < 62; ++j) {
        ITER_COMMON;
        tmin = fminf(tmin, (j < jmax) ? tt : BIG_T);
    }
    tmin = fminf(tmin, __shfl_xor(tmin, 1));   // share max log-weight across the pair
    float mK = tmin * LOG2E;

    // ---- pass 2: branchless accumulate with known max ----
    float den = 0.f;
    float num[32];
#pragma unroll
    for (int c = 0; c < 32; ++c) num[c] = 0.f;

#pragma unroll 2
    for (int j = 0; j < 62; ++j) {
        ITER_COMMON;
        float ta = (j < jmax) ? tt : BIG_T;
        float wgt = fast_exp2(fmaf(ta, -LOG2E, mK));   // exp(lw - m), 0 when masked
        den += wgt;
        const float4* fp = reinterpret_cast<const float4*>(featT + (size_t)ci * 32);
#pragma unroll
        for (int q = 0; q < 8; ++q) {
            float4 f = fp[q];
            num[4 * q + 0] = fmaf(wgt, f.x, num[4 * q + 0]);
            num[4 * q + 1] = fmaf(wgt, f.y, num[4 * q + 1]);
            num[4 * q + 2] = fmaf(wgt, f.z, num[4 * q + 2]);
            num[4 * q + 3] = fmaf(wgt, f.w, num[4 * q + 3]);
        }
    }
#undef ITER_COMMON

    // ---- merge the pair and write ----
    den += __shfl_xor(den, 1);
    float inv = 1.f / fmaxf(den, 1e-8f);
#pragma unroll
    for (int c = 0; c < 32; ++c) {
        float nt = num[c] + __shfl_xor(num[c], 1);
        if ((c >> 4) == h) out[c * 262144 + vox] = nt * inv;
    }
}

// ---------------- launch ----------------
extern "C" void kernel_launch(void* const* d_in, const int* in_sizes, int n_in,
                              void* d_out, int out_size, void* d_ws, size_t ws_size,
                              hipStream_t stream) {
    const float* feat = (const float*)d_in[0];    // [1][32][32][32][32]
    const float* guide = (const float*)d_in[1];   // [1][3][64][64][64]
    const float* sxr = (const float*)d_in[2];
    const float* syr = (const float*)d_in[3];
    const float* szr = (const float*)d_in[4];
    const float* srr = (const float*)d_in[5];
    float* out = (float*)d_out;                   // [1][32][64][64][64]

    char* ws = (char*)d_ws;
    float4* param4 = (float4*)ws;                 // 32768 * 32 B = 1 MB
    float* sigEff = (float*)(ws + 1048576);       // 128 KB
    float* featT = (float*)(ws + 1179648);        // 4 MB

    prepA<<<128, 256, 0, stream>>>(sxr, syr, szr, srr, param4, sigEff);
    prepB<<<128, 256, 0, stream>>>(guide, param4);
    prepT<<<1024, 256, 0, stream>>>(feat, featT);
    jbu_main<<<2048, 256, 0, stream>>>(guide, param4, sigEff, featT, out);
}

// Round 3
// 98.538 us; speedup vs baseline: 3.9445x; 3.9445x over previous
//
#include <hip/hip_runtime.h>

typedef float f32x2 __attribute__((ext_vector_type(2)));
typedef _Float16 h2 __attribute__((ext_vector_type(2)));

constexpr float LOG2E = 1.4426950408889634f;

// ---- packed offset table: 123 offsets (r2<=9) sorted by r2; pk = (dx+3)|(dy+3)<<4|(dz+3)<<8|r2<<12 ----
struct OffTab { int v[123]; };
constexpr OffTab make_off() {
    OffTab t{}; int n = 0;
    for (int rr = 0; rr <= 9; ++rr)
        for (int a = -3; a <= 3; ++a)
            for (int b = -3; b <= 3; ++b)
                for (int c = -3; c <= 3; ++c)
                    if (a*a + b*b + c*c == rr)
                        t.v[n++] = (a + 3) | ((b + 3) << 4) | ((c + 3) << 8) | (rr << 12);
    return t;
}
__constant__ OffTab OFFT = make_off();

__device__ __forceinline__ float fast_exp2(float x) { return __builtin_amdgcn_exp2f(x); }

// ---------------- prep A: per-LR-voxel sigma reciprocals (record slot 0) + sigma_eff ----------------
__global__ void prepA(const float* __restrict__ sxr, const float* __restrict__ syr,
                      const float* __restrict__ szr, const float* __restrict__ srr,
                      float4* __restrict__ param4, float* __restrict__ sigEff) {
    int t = blockIdx.x * 256 + threadIdx.x;   // 32768 total
    float sx = fmaxf(expf(sxr[t]), 1e-6f);
    float sy = fmaxf(expf(syr[t]), 1e-6f);
    float sz = fmaxf(expf(szr[t]), 1e-6f);
    float sr = fmaxf(expf(srr[t]), 1e-6f);
    float a = 0.5f / (sx * sx);
    float b = 0.5f / (sy * sy);
    float c = 0.5f / (sz * sz);
    float d = 1.0f / (2.0f * sr * sr + 1e-8f);
    param4[2 * t] = make_float4(a, b, c, d);
    sigEff[t] = fmaxf(sx, fmaxf(sy, sz));
}

// ---------------- prep B: guide 64^3 -> 32^3 trilinear-antialias downsample (record slot 1) ----------------
__device__ __forceinline__ void mk_taps(int j, int idx[4], float wt[4]) {
    float s = 0.f;
#pragma unroll
    for (int k = 0; k < 4; ++k) {
        int i = 2 * j - 1 + k;
        float w = (k == 0 || k == 3) ? 0.25f : 0.75f;
        bool ok = (i >= 0) && (i < 64);
        wt[k] = ok ? w : 0.f;
        idx[k] = ok ? i : 0;
        s += wt[k];
    }
    float inv = 1.f / s;
#pragma unroll
    for (int k = 0; k < 4; ++k) wt[k] *= inv;
}

__global__ void prepB(const float* __restrict__ guide, float4* __restrict__ param4) {
    int t = blockIdx.x * 256 + threadIdx.x;   // 32768 total
    int w = t & 31, v = (t >> 5) & 31, u = t >> 10;
    int iu[4], iv[4], iw[4];
    float wu[4], wv[4], ww[4];
    mk_taps(u, iu, wu);
    mk_taps(v, iv, wv);
    mk_taps(w, iw, ww);
    float g0 = 0.f, g1 = 0.f, g2 = 0.f;
#pragma unroll
    for (int a = 0; a < 4; ++a) {
#pragma unroll
        for (int b = 0; b < 4; ++b) {
            float wab = wu[a] * wv[b];
            int base = iu[a] * 4096 + iv[b] * 64;
#pragma unroll
            for (int c = 0; c < 4; ++c) {
                float wt = wab * ww[c];
                int gi = base + iw[c];
                g0 += wt * guide[gi];
                g1 += wt * guide[262144 + gi];
                g2 += wt * guide[524288 + gi];
            }
        }
    }
    param4[2 * t + 1] = make_float4(g0, g1, g2, 0.f);
}

// ---------------- prep T: feat [c][u][v][w] -> featH [u][v][w][c] in f16 ----------------
__global__ void prepT(const float* __restrict__ feat, _Float16* __restrict__ featH) {
    __shared__ float tile[32][33];
    int uv = blockIdx.x;            // 1024 blocks, one per (u,v)
    int u = uv >> 5, v = uv & 31;
    int col = threadIdx.x & 31;
    int row = threadIdx.x >> 5;     // 0..7
#pragma unroll
    for (int it = 0; it < 4; ++it) {
        int c = row + it * 8;
        tile[c][col] = feat[((c * 32 + u) * 32 + v) * 32 + col];
    }
    __syncthreads();
#pragma unroll
    for (int it = 0; it < 4; ++it) {
        int w = row + it * 8;
        featH[((u * 32 + v) * 32 + w) * 32 + col] = (_Float16)tile[col][w];
    }
}

// ---------------- main kernel: wave = 8x8 (Y,Z) tile at fixed X; 2x2 quads share LR cell ----------------
__global__ __launch_bounds__(256)
void jbu_main(const float* __restrict__ guide, const float4* __restrict__ param4,
              const float* __restrict__ sigEff, const _Float16* __restrict__ featH,
              float* __restrict__ out) {
    __shared__ float sm[4][64][34];
    int tid = threadIdx.x;
    int widx = __builtin_amdgcn_readfirstlane(tid >> 6);
    int l = tid & 63;
    // XCD-bijective swizzle: XCD k owns X in [8k, 8k+8)
    int bsw = (blockIdx.x & 7) * 128 + (blockIdx.x >> 3);
    int g = bsw * 4 + widx;                 // 4096 waves
    int X = g >> 6;
    int Y0 = ((g >> 3) & 7) << 3;
    int Z0 = (g & 7) << 3;
    int y = l >> 3, z = l & 7;
    int Y = Y0 + y, Z = Z0 + z;
    int h = ((y & 1) << 1) | (z & 1);       // channel-quarter / quad slot
    int vox = (X << 12) + (Y << 6) + Z;

    float G0 = guide[vox];
    float G1 = guide[262144 + vox];
    float G2 = guide[524288 + vox];

    // sigma_eff_hr: 2x trilinear upsample with clamped taps -> R2i
    int x0 = max((X - 1) >> 1, 0), x1 = min(((X - 1) >> 1) + 1, 31);
    int y0 = max((Y - 1) >> 1, 0), y1 = min(((Y - 1) >> 1) + 1, 31);
    int z0 = max((Z - 1) >> 1, 0), z1 = min(((Z - 1) >> 1) + 1, 31);
    float wx1 = (X & 1) ? 0.25f : 0.75f, wx0 = 1.f - wx1;
    float wy1 = (Y & 1) ? 0.25f : 0.75f, wy0 = 1.f - wy1;
    float wz1 = (Z & 1) ? 0.25f : 0.75f, wz0 = 1.f - wz1;
#define SG(i, j, k) sigEff[((i) * 32 + (j)) * 32 + (k)]
    float se =
        wx0 * (wy0 * (wz0 * SG(x0, y0, z0) + wz1 * SG(x0, y0, z1)) +
               wy1 * (wz0 * SG(x0, y1, z0) + wz1 * SG(x0, y1, z1))) +
        wx1 * (wy0 * (wz0 * SG(x1, y0, z0) + wz1 * SG(x1, y0, z1)) +
               wy1 * (wz0 * SG(x1, y1, z0) + wz1 * SG(x1, y1, z1)));
#undef SG
    float Rf = fminf(fmaxf(ceilf(2.f * se), 1.f), 3.f);
    int R2i = (int)(Rf * Rf + 0.5f);
    bool a9 = __any((int)(R2i >= 9));
    bool a4 = __any((int)(R2i >= 4));
    int nmax = a9 ? 123 : (a4 ? 33 : 7);

    int ucm = (X >> 1) - 3;                 // wave-uniform
    int vcm = (Y >> 1) - 3, wcm = (Z >> 1) - 3;
    float Xh = (float)X - 0.5f, Yh = (float)Y - 0.5f, Zh = (float)Z - 0.5f;

    f32x2 num2[4][4];
#pragma unroll
    for (int r = 0; r < 4; ++r)
#pragma unroll
        for (int p = 0; p < 4; ++p) num2[r][p] = {0.f, 0.f};
    float den = 0.f, M = -3.0e38f;

    // 1-deep software prefetch
    int pk_n = OFFT.v[0];
    int Ui_n = min(max(ucm + (pk_n & 15), 0), 31);
    int Vi_n = min(max(vcm + ((pk_n >> 4) & 15), 0), 31);
    int Wi_n = min(max(wcm + ((pk_n >> 8) & 15), 0), 31);
    int ci_n = (Ui_n << 10) | (Vi_n << 5) | Wi_n;
    float4 A_n = param4[2 * ci_n];
    float4 B_n = param4[2 * ci_n + 1];
    float4 F_n = *(const float4*)(featH + ci_n * 32 + h * 8);

    for (int o = 0; o < nmax; ++o) {
        int pk = pk_n, Ui = Ui_n, Vi = Vi_n, Wi = Wi_n;
        float4 A = A_n, B = B_n, F = F_n;
        int on = min(o + 1, nmax - 1);
        pk_n = OFFT.v[on];
        Ui_n = min(max(ucm + (pk_n & 15), 0), 31);
        Vi_n = min(max(vcm + ((pk_n >> 4) & 15), 0), 31);
        Wi_n = min(max(wcm + ((pk_n >> 8) & 15), 0), 31);
        ci_n = (Ui_n << 10) | (Vi_n << 5) | Wi_n;
        A_n = param4[2 * ci_n];
        B_n = param4[2 * ci_n + 1];
        F_n = *(const float4*)(featH + ci_n * 32 + h * 8);

        int r2 = pk >> 12;
        float ddx = fmaf(-2.f, (float)Ui, Xh);
        float ddy = fmaf(-2.f, (float)Vi, Yh);
        float ddz = fmaf(-2.f, (float)Wi, Zh);
        float tt = fmaf(ddx * ddx, A.x, fmaf(ddy * ddy, A.y, ddz * ddz * A.z));
        float d0 = G0 - B.x, d1 = G1 - B.y, d2 = G2 - B.z;
        tt = fmaf(fmaf(d0, d0, fmaf(d1, d1, d2 * d2)), A.w, tt);
        float s = tt * (-LOG2E);            // log2-weight
        s = (r2 <= R2i) ? s : -1.0e30f;

        bool trig = (s - M) > 8.0f;         // deferred rescale: only on >2^8 improvement
        if (__any((int)trig)) {
            float Mn = trig ? s : M;
            float sc = fast_exp2(M - Mn);
            M = Mn;
            den *= sc;
            float s1 = __shfl_xor(sc, 1), s8 = __shfl_xor(sc, 8), s9 = __shfl_xor(sc, 9);
            f32x2 c0 = {sc, sc}, c1 = {s1, s1}, c2 = {s8, s8}, c3 = {s9, s9};
#pragma unroll
            for (int p = 0; p < 4; ++p) {
                num2[0][p] *= c0;
                num2[1][p] *= c1;
                num2[2][p] *= c2;
                num2[3][p] *= c3;
            }
        }
        float wgt = fast_exp2(s - M);       // 0 when masked
        den += wgt;
        float w1 = __shfl_xor(wgt, 1), w8 = __shfl_xor(wgt, 8), w9 = __shfl_xor(wgt, 9);

        h2 q0 = __builtin_bit_cast(h2, F.x);
        h2 q1 = __builtin_bit_cast(h2, F.y);
        h2 q2 = __builtin_bit_cast(h2, F.z);
        h2 q3 = __builtin_bit_cast(h2, F.w);
        f32x2 f0 = {(float)q0.x, (float)q0.y};
        f32x2 f1 = {(float)q1.x, (float)q1.y};
        f32x2 f2 = {(float)q2.x, (float)q2.y};
        f32x2 f3 = {(float)q3.x, (float)q3.y};
        f32x2 w0v = {wgt, wgt}, w1v = {w1, w1}, w2v = {w8, w8}, w3v = {w9, w9};
        num2[0][0] += f0 * w0v; num2[0][1] += f1 * w0v; num2[0][2] += f2 * w0v; num2[0][3] += f3 * w0v;
        num2[1][0] += f0 * w1v; num2[1][1] += f1 * w1v; num2[1][2] += f2 * w1v; num2[1][3] += f3 * w1v;
        num2[2][0] += f0 * w2v; num2[2][1] += f1 * w2v; num2[2][2] += f2 * w2v; num2[2][3] += f3 * w2v;
        num2[3][0] += f0 * w3v; num2[3][1] += f1 * w3v; num2[3][2] += f2 * w3v; num2[3][3] += f3 * w3v;
    }

    // ---- epilogue: normalize, transpose via LDS, coalesced channel-plane stores ----
    float invd = 1.0f / fmaxf(den, 1e-8f);
    float i1 = __shfl_xor(invd, 1), i8 = __shfl_xor(invd, 8), i9 = __shfl_xor(invd, 9);
    f32x2 iv0 = {invd, invd}, iv1 = {i1, i1}, iv2 = {i8, i8}, iv3 = {i9, i9};
    int cb = h * 8;
    int v0 = l, v1 = l ^ 1, v2 = l ^ 8, v3 = l ^ 9;
#pragma unroll
    for (int p = 0; p < 4; ++p) {
        *(f32x2*)&sm[widx][v0][cb + 2 * p] = num2[0][p] * iv0;
        *(f32x2*)&sm[widx][v1][cb + 2 * p] = num2[1][p] * iv1;
        *(f32x2*)&sm[widx][v2][cb + 2 * p] = num2[2][p] * iv2;
        *(f32x2*)&sm[widx][v3][cb + 2 * p] = num2[3][p] * iv3;
    }
    __syncthreads();
#pragma unroll
    for (int p = 0; p < 16; ++p) {
        f32x2 v = *(const f32x2*)&sm[widx][l][2 * p];
        out[(2 * p) * 262144 + vox] = v.x;
        out[(2 * p + 1) * 262144 + vox] = v.y;
    }
}

// ---------------- launch ----------------
extern "C" void kernel_launch(void* const* d_in, const int* in_sizes, int n_in,
                              void* d_out, int out_size, void* d_ws, size_t ws_size,
                              hipStream_t stream) {
    const float* feat = (const float*)d_in[0];    // [1][32][32][32][32]
    const float* guide = (const float*)d_in[1];   // [1][3][64][64][64]
    const float* sxr = (const float*)d_in[2];
    const float* syr = (const float*)d_in[3];
    const float* szr = (const float*)d_in[4];
    const float* srr = (const float*)d_in[5];
    float* out = (float*)d_out;                   // [1][32][64][64][64]

    char* ws = (char*)d_ws;
    float4* param4 = (float4*)ws;                 // 32768 * 32 B = 1 MB (A,B interleaved)
    float* sigEff = (float*)(ws + 1048576);       // 128 KB
    _Float16* featH = (_Float16*)(ws + 1179648);  // 2 MB, 64B records

    prepA<<<128, 256, 0, stream>>>(sxr, syr, szr, srr, param4, sigEff);
    prepB<<<128, 256, 0, stream>>>(guide, param4);
    prepT<<<1024, 256, 0, stream>>>(feat, featH);
    jbu_main<<<1024, 256, 0, stream>>>(guide, param4, sigEff, featH, out);
}